// Round 11
// baseline (41.792 us; speedup 1.0000x reference)
//
#include <hip/hip_runtime.h>
#include <math.h>

#define FF 64
#define FP1 65
#define BB 32
#define LL 128
#define NBL 4096        // BB*LL
#define NIJ 4096        // FF*FF

typedef __attribute__((ext_vector_type(8))) short short8;
typedef __attribute__((ext_vector_type(4))) float f32x4;

__device__ __forceinline__ unsigned short f2b(float f) {   // f32 -> bf16 RNE
    union { float f; unsigned u; } v; v.f = f;
    unsigned r = v.u + 0x7fffu + ((v.u >> 16) & 1u);
    return (unsigned short)(r >> 16);
}
__device__ __forceinline__ float b2f(unsigned short h) {
    union { unsigned u; float f; } v; v.u = ((unsigned)h) << 16; return v.f;
}

// ---- ws layout (bytes) ----
#define OFF_BH   0ull            // slabB hi (j-major B-frags) 512 KB
#define OFF_BL   524288ull       // slabB lo 512 KB
#define OFF_FLAG 1048576ull      // 4 B
#define WS_NEED  1048640ull

// ============ stage 1: slab k=0 slice -> bf16 hi/lo B-fragments (n = j*64+i); zero flag ============
__global__ void build_slabB(const float* __restrict__ inter,
                            unsigned short* __restrict__ bH,
                            unsigned short* __restrict__ bL,
                            int* __restrict__ flag) {
    const size_t t = (size_t)blockIdx.x * 256 + threadIdx.x;   // 262144 total
    if (t == 0) *flag = 0;
    const int e = (int)(t & 7);
    const int lane = (int)((t >> 3) & 63);
    const int fn = (int)((t >> 9) & 255);
    const int ks = (int)(t >> 17);
    const int n = fn * 16 + (lane & 15);
    const int i = n & 63;
    const int j = n >> 6;
    const int m = ks * 32 + ((lane >> 4) & 3) * 8 + e;
    const float v = inter[((size_t)(i * FF + j) * FF + m) * FP1];
    const unsigned short h = f2b(v);
    bH[t] = h;
    bL[t] = f2b(v - b2f(h));
}

// ============ stage 2: fused GEMM (split-bf16 MFMA) + col-softmax + matvec ============
// grid 128 (fm = 32-bl tile), block 512 = 8 waves; wave w owns j = w*8..w*8+7.
// 2 M-frags per block: B-frag loads amortized 2x -> per-XCD L2 traffic halved vs r10.
__launch_bounds__(512, 2)
__global__ void fused_mfma(const float* __restrict__ x,
                           const unsigned short* __restrict__ bH,
                           const unsigned short* __restrict__ bL,
                           float* __restrict__ out,
                           int* __restrict__ flag) {
    __shared__ float xT[FF][33];         // xT[j][bl_local 0..31]  8.4 KB
    __shared__ float part[8][FF][33];    // per-wave out partials [i][bl_local]  67.6 KB
    __shared__ float wmn[8];

    const int tid = threadIdx.x;         // 512
    const int w = tid >> 6, lane = tid & 63;
    const int fm = blockIdx.x;           // 0..127
    const int bl0 = fm * 32;
    const int hi4 = lane >> 4;           // 0..3
    const int c15 = lane & 15;

    #pragma unroll
    for (int p = 0; p < 4; ++p) {        // stage xT: 2048 floats, coalesced in j
        const int idx = tid + p * 512;
        const int bl_local = idx >> 6, j = idx & 63;
        xT[j][bl_local] = x[(size_t)(bl0 + bl_local) * FF + j];
    }

    // build A fragments (2 M-frags) in registers
    short8 aH[2][2], aL[2][2];           // [mf][ks]
    #pragma unroll
    for (int mf = 0; mf < 2; ++mf)
        #pragma unroll
        for (int ks = 0; ks < 2; ++ks) {
            const float* xp = x + (size_t)(bl0 + mf * 16 + c15) * FF + ks * 32 + hi4 * 8;
            const float4 v0 = *(const float4*)xp;
            const float4 v1 = *(const float4*)(xp + 4);
            float vv[8] = {v0.x, v0.y, v0.z, v0.w, v1.x, v1.y, v1.z, v1.w};
            unsigned short hh[8], ll[8];
            #pragma unroll
            for (int e = 0; e < 8; ++e) {
                hh[e] = f2b(vv[e]);
                ll[e] = f2b(vv[e] - b2f(hh[e]));
            }
            aH[mf][ks] = *(const short8*)hh;
            aL[mf][ks] = *(const short8*)ll;
        }
    __syncthreads();

    f32x4 racc[2][4];                    // [mf][q]
    #pragma unroll
    for (int mf = 0; mf < 2; ++mf)
        #pragma unroll
        for (int q = 0; q < 4; ++q) racc[mf][q] = (f32x4){0.f, 0.f, 0.f, 0.f};
    f32x4 mn4 = (f32x4){INFINITY, INFINITY, INFINITY, INFINITY};

    const bool wrT = ((fm & 3) == 3) && (hi4 == 3);
    float* out1 = out + (size_t)BB * LL * FF + (size_t)(fm >> 2) * NIJ;

    #pragma unroll 1
    for (int jj = 0; jj < 8; ++jj) {
        const int j = w * 8 + jj;
        f32x4 acc[2][4];
        #pragma unroll
        for (int mf = 0; mf < 2; ++mf)
            #pragma unroll
            for (int q = 0; q < 4; ++q) acc[mf][q] = (f32x4){0.f, 0.f, 0.f, 0.f};
        #pragma unroll
        for (int ks = 0; ks < 2; ++ks) {
            #pragma unroll
            for (int q = 0; q < 4; ++q) {
                const size_t bb = (((size_t)ks * 256 + j * 4 + q) * 64 + lane) * 8;
                const short8 bHf = *(const short8*)(bH + bb);
                const short8 bLf = *(const short8*)(bL + bb);
                #pragma unroll
                for (int mf = 0; mf < 2; ++mf) {
                    acc[mf][q] = __builtin_amdgcn_mfma_f32_16x16x32_bf16(aH[mf][ks], bHf, acc[mf][q], 0, 0, 0);
                    acc[mf][q] = __builtin_amdgcn_mfma_f32_16x16x32_bf16(aH[mf][ks], bLf, acc[mf][q], 0, 0, 0);
                    acc[mf][q] = __builtin_amdgcn_mfma_f32_16x16x32_bf16(aL[mf][ks], bHf, acc[mf][q], 0, 0, 0);
                }
            }
        }
        // per-mf: z = 7*D0 ; softmax over i = {16 lanes} x {4 frags}; racc += w * x_j
        #pragma unroll
        for (int mf = 0; mf < 2; ++mf) {
            f32x4 z[4], mxv;
            #pragma unroll
            for (int q = 0; q < 4; ++q) {
                z[q] = acc[mf][q] * 7.0f;
                #pragma unroll
                for (int c = 0; c < 4; ++c) mn4[c] = fminf(mn4[c], z[q][c]);
            }
            #pragma unroll
            for (int c = 0; c < 4; ++c)
                mxv[c] = fmaxf(fmaxf(z[0][c], z[1][c]), fmaxf(z[2][c], z[3][c]));
            #pragma unroll
            for (int o = 1; o < 16; o <<= 1)
                #pragma unroll
                for (int c = 0; c < 4; ++c) mxv[c] = fmaxf(mxv[c], __shfl_xor(mxv[c], o));
            f32x4 e[4], s = (f32x4){0.f, 0.f, 0.f, 0.f};
            #pragma unroll
            for (int q = 0; q < 4; ++q) {
                #pragma unroll
                for (int c = 0; c < 4; ++c) e[q][c] = __expf(z[q][c] - mxv[c]);
                s += e[q];
            }
            #pragma unroll
            for (int o = 1; o < 16; o <<= 1)
                #pragma unroll
                for (int c = 0; c < 4; ++c) s[c] += __shfl_xor(s[c], o);
            f32x4 inv, xbv;
            #pragma unroll
            for (int c = 0; c < 4; ++c) inv[c] = 1.0f / s[c];
            #pragma unroll
            for (int c = 0; c < 4; ++c) xbv[c] = xT[j][mf * 16 + hi4 * 4 + c];
            #pragma unroll
            for (int q = 0; q < 4; ++q) {
                const f32x4 wq = e[q] * inv;
                racc[mf][q] += wq * xbv;
                if (wrT && mf == 1) out1[(q * 16 + c15) * 64 + j] = wq[3];   // bl_local 31 -> l=127
            }
        }
    }

    #pragma unroll
    for (int mf = 0; mf < 2; ++mf)
        #pragma unroll
        for (int q = 0; q < 4; ++q)
            #pragma unroll
            for (int r = 0; r < 4; ++r)
                part[w][q * 16 + c15][mf * 16 + hi4 * 4 + r] = racc[mf][q][r];

    float mn = fminf(fminf(mn4[0], mn4[1]), fminf(mn4[2], mn4[3]));
    #pragma unroll
    for (int o = 1; o < 64; o <<= 1) mn = fminf(mn, __shfl_xor(mn, o));
    if (lane == 0) wmn[w] = mn;
    __syncthreads();

    #pragma unroll
    for (int p = 0; p < 4; ++p) {        // deterministic cross-wave j-reduction
        const int idx = tid + p * 512;
        const int bl_local = idx >> 6, i = idx & 63;
        float a = 0.f;
        #pragma unroll
        for (int ww = 0; ww < 8; ++ww) a += part[ww][i][bl_local];
        out[(size_t)(bl0 + bl_local) * FF + i] = a;
    }
    if (tid == 0) {
        float m2 = wmn[0];
        #pragma unroll
        for (int ww = 1; ww < 8; ++ww) m2 = fminf(m2, wmn[ww]);
        if (!(m2 >= 10.5f)) atomicOr(flag, 1);   // also catches NaN
    }
}

// ============ fallback slab build (small-ws path only) ============
__global__ void build_slab0(const float* __restrict__ inter, float* __restrict__ slab0T) {
    int t = blockIdx.x * blockDim.x + threadIdx.x;
    if (t < FF * FF * FF) {
        int m = t >> 12;
        int ij = t & 4095;
        slab0T[t] = inter[((size_t)ij * FF + m) * FP1];
    }
}

// ==================== exact sequential fallback / repair (verified round-1) ====================
__launch_bounds__(1024, 1)
__global__ void coil_main(const float* __restrict__ x,
                          const float* __restrict__ inter,
                          const float* __restrict__ slab0T,
                          float* __restrict__ out,
                          int useSlab,
                          const int* __restrict__ flag) {
    if (flag && *flag == 0) return;   // certificate held: parallel path already correct

    __shared__ float Tlds[FF][FP1];
    __shared__ float selr[FF][FP1];
    __shared__ float s_l[FF], hiW[FF], loW[FF];
    __shared__ float zsc[FP1], swW[FP1], scoresAcc[FP1];
    __shared__ float chunkA[8][FP1 + 3];
    __shared__ int IL[FF], JL[FF];
    __shared__ int nIJ[2];
    __shared__ int Klist[FP1];
    __shared__ float Kw[FP1];
    __shared__ int nK;
    __shared__ float redmx;

    const int b = blockIdx.x;
    const int tid = threadIdx.x;
    const int wave = tid >> 6;
    const int lane = tid & 63;

    for (int idx = tid; idx < FF * FP1; idx += 1024)
        ((float*)Tlds)[idx] = 1.0f / FF;

    const float* xb = x + (size_t)b * LL * FF;
    float* out0 = out + (size_t)b * LL * FF;
    float* out1 = out + (size_t)BB * LL * FF + (size_t)b * FF * FF;

    for (int l = 0; l < LL; ++l) {
        __syncthreads();
        if (tid < FF) s_l[tid] = xb[l * FF + tid];
        __syncthreads();
        if (wave == 0) {
            float z = s_l[lane] / 0.001f;
            float mx = z;
            for (int o = 32; o > 0; o >>= 1) mx = fmaxf(mx, __shfl_xor(mx, o));
            float e = expf(z - mx);
            float sm = e;
            for (int o = 32; o > 0; o >>= 1) sm += __shfl_xor(sm, o);
            float w = e / sm;
            hiW[lane] = w;
            unsigned long long msk = __ballot(w > 1e-16f);
            int pos = (int)__popcll(msk & ((1ull << lane) - 1ull));
            if (w > 1e-16f) JL[pos] = lane;
            if (lane == 0) nIJ[1] = (int)__popcll(msk);
        } else if (wave == 1) {
            float z = 1.0f - s_l[lane] / 0.001f;
            float mx = z;
            for (int o = 32; o > 0; o >>= 1) mx = fmaxf(mx, __shfl_xor(mx, o));
            float e = expf(z - mx);
            float sm = e;
            for (int o = 32; o > 0; o >>= 1) sm += __shfl_xor(sm, o);
            float w = e / sm;
            loW[lane] = w;
            unsigned long long msk = __ballot(w > 1e-16f);
            int pos = (int)__popcll(msk & ((1ull << lane) - 1ull));
            if (w > 1e-16f) IL[pos] = lane;
            if (lane == 0) nIJ[0] = (int)__popcll(msk);
        }
        if (tid < FP1) scoresAcc[tid] = 0.0f;
        __syncthreads();

        const int nI = nIJ[0], nJ = nIJ[1];
        const int npairs = nI * nJ;
        for (int pbase = 0; pbase < npairs; pbase += 8) {
            int prem = npairs - pbase; if (prem > 8) prem = 8;
            int p_local = wave >> 1, half = wave & 1;
            if (p_local < prem) {
                int p = pbase + p_local;
                int i = IL[p / nJ];
                int jx = JL[p % nJ];
                float vv = loW[i] * hiW[jx];
                int k = half * 32 + lane;
                bool act = half ? (lane < 33) : (lane < 32);
                if (act) {
                    const float* base = inter + (size_t)(i * FF + jx) * (FF * FP1) + k;
                    const float* nsv = (k == 0) ? s_l : &Tlds[k - 1][0];
                    float acc = 0.0f;
                    #pragma unroll 16
                    for (int m = 0; m < FF; ++m) acc += base[m * FP1] * nsv[m];
                    chunkA[p_local][k] = vv * acc;
                }
            }
            __syncthreads();
            if (tid < FP1) {
                float a = scoresAcc[tid];
                for (int pl = 0; pl < prem; ++pl) a += chunkA[pl][tid];
                scoresAcc[tid] = a;
            }
            __syncthreads();
        }
        if (tid < FP1) zsc[tid] = scoresAcc[tid] / 0.001f;
        __syncthreads();
        if (tid == 0) {
            float mx = zsc[0];
            for (int k = 1; k < FP1; ++k) mx = fmaxf(mx, zsc[k]);
            redmx = mx;
        }
        __syncthreads();
        if (tid < FP1) zsc[tid] = expf(zsc[tid] - redmx);
        __syncthreads();
        if (tid == 0) {
            float sm = 0.0f;
            for (int k = 0; k < FP1; ++k) sm += zsc[k];
            int cnt = 0;
            for (int k = 0; k < FP1; ++k) {
                float w = zsc[k] / sm;
                swW[k] = w;
                if (w > 1e-14f) { Klist[cnt] = k; Kw[cnt] = w; ++cnt; }
            }
            nK = cnt;
        }
        __syncthreads();

        float ax = 0.f, ay = 0.f, az = 0.f, aw = 0.f;
        const int ij0 = tid * 4;
        for (int kk = 0; kk < nK; ++kk) {
            int k = Klist[kk];
            float wk = Kw[kk];
            float dx = 0.f, dy = 0.f, dz = 0.f, dw = 0.f;
            if (k == 0 && useSlab) {
                const float4* sp = (const float4*)slab0T;
                #pragma unroll 8
                for (int m = 0; m < FF; ++m) {
                    float4 f = sp[m * (FF * FF / 4) + tid];
                    float ns = s_l[m];
                    dx += f.x * ns; dy += f.y * ns; dz += f.z * ns; dw += f.w * ns;
                }
            } else {
                const float* nsv = (k == 0) ? s_l : &Tlds[k - 1][0];
                const float* bp = inter + (size_t)ij0 * (FF * FP1) + k;
                #pragma unroll 8
                for (int m = 0; m < FF; ++m) {
                    float ns = nsv[m];
                    dx += bp[m * FP1] * ns;
                    dy += bp[m * FP1 + FF * FP1] * ns;
                    dz += bp[m * FP1 + 2 * FF * FP1] * ns;
                    dw += bp[m * FP1 + 3 * FF * FP1] * ns;
                }
            }
            ax += wk * dx; ay += wk * dy; az += wk * dz; aw += wk * dw;
        }
        {
            int ii = tid >> 4;
            int jj = (tid & 15) * 4;
            selr[jj + 0][ii] = ax; selr[jj + 1][ii] = ay;
            selr[jj + 2][ii] = az; selr[jj + 3][ii] = aw;
        }
        __syncthreads();
        if (tid < FF) {
            int jcol = tid;
            float mx = -INFINITY;
            for (int i2 = 0; i2 < FF; ++i2) mx = fmaxf(mx, selr[jcol][i2] * 7.0f);
            float sm = 0.0f;
            for (int i2 = 0; i2 < FF; ++i2) {
                float e = expf(selr[jcol][i2] * 7.0f - mx);
                selr[jcol][i2] = e; sm += e;
            }
            for (int i2 = 0; i2 < FF; ++i2) Tlds[jcol][i2] = selr[jcol][i2] / sm;
        }
        __syncthreads();
        if (tid < FF) {
            float acc2 = 0.0f;
            for (int j2 = 0; j2 < FF; ++j2) acc2 += Tlds[j2][tid] * s_l[j2];
            out0[l * FF + tid] = acc2;
        }
    }
    __syncthreads();
    for (int idx = tid; idx < FF * FF; idx += 1024) {
        int i2 = idx >> 6, j2 = idx & 63;
        out1[idx] = Tlds[j2][i2];
    }
}

extern "C" void kernel_launch(void* const* d_in, const int* in_sizes, int n_in,
                              void* d_out, int out_size, void* d_ws, size_t ws_size,
                              hipStream_t stream) {
    const float* x = (const float*)d_in[0];
    const float* inter = (const float*)d_in[1];
    float* outp = (float*)d_out;
    char* ws = (char*)d_ws;

    if (ws_size >= WS_NEED) {
        unsigned short* bH = (unsigned short*)(ws + OFF_BH);
        unsigned short* bL = (unsigned short*)(ws + OFF_BL);
        int* flag = (int*)(ws + OFF_FLAG);

        build_slabB<<<dim3(1024), dim3(256), 0, stream>>>(inter, bH, bL, flag);
        fused_mfma<<<dim3(128), dim3(512), 0, stream>>>(x, bH, bL, outp, flag);
        // repair: no-op when certificate holds; exact recompute otherwise
        coil_main<<<dim3(BB), dim3(1024), 0, stream>>>(x, inter, (const float*)0, outp, 0, flag);
    } else {
        float* slab0T = (float*)ws;
        int useSlab = (ws_size >= (size_t)FF * FF * FF * sizeof(float)) ? 1 : 0;
        if (useSlab)
            build_slab0<<<dim3(1024), dim3(256), 0, stream>>>(inter, slab0T);
        coil_main<<<dim3(BB), dim3(1024), 0, stream>>>(x, inter, slab0T, outp, useSlab, (const int*)0);
    }
}

// Round 12
// 34.600 us; speedup vs baseline: 1.2079x; 1.2079x over previous
//
#include <hip/hip_runtime.h>
#include <math.h>

#define FF 64
#define FP1 65
#define BB 32
#define LL 128
#define NBL 4096        // BB*LL
#define NIJ 4096        // FF*FF

typedef __attribute__((ext_vector_type(8))) short short8;
typedef __attribute__((ext_vector_type(4))) float f32x4;

__device__ __forceinline__ unsigned short f2b(float f) {   // f32 -> bf16 RNE
    union { float f; unsigned u; } v; v.f = f;
    unsigned r = v.u + 0x7fffu + ((v.u >> 16) & 1u);
    return (unsigned short)(r >> 16);
}
__device__ __forceinline__ float b2f(unsigned short h) {
    union { unsigned u; float f; } v; v.u = ((unsigned)h) << 16; return v.f;
}

// ---- ws layout (bytes) ----
#define OFF_BH   0ull            // slabB hi (j-major B-frags) 512 KB
#define OFF_BL   524288ull       // slabB lo 512 KB
#define OFF_FLAG 1048576ull      // 4 B
#define WS_NEED  1048640ull

// ============ stage 1: slab k=0 slice -> bf16 hi/lo B-fragments (n = j*64+i); zero flag ============
// Each thread handles 2 consecutive e (packed uint stores).
__global__ void build_slabB(const float* __restrict__ inter,
                            unsigned short* __restrict__ bH,
                            unsigned short* __restrict__ bL,
                            int* __restrict__ flag) {
    const size_t t2 = (size_t)blockIdx.x * 256 + threadIdx.x;  // 131072 total
    if (t2 == 0) *flag = 0;
    const size_t t = t2 * 2;
    const int e = (int)(t & 7);
    const int lane = (int)((t >> 3) & 63);
    const int fn = (int)((t >> 9) & 255);
    const int ks = (int)(t >> 17);
    const int n = fn * 16 + (lane & 15);
    const int i = n & 63;
    const int j = n >> 6;
    const int m = ks * 32 + ((lane >> 4) & 3) * 8 + e;
    const float* ip = inter + ((size_t)(i * FF + j) * FF + m) * FP1;
    const float v0 = ip[0];
    const float v1 = ip[FP1];
    const unsigned short h0 = f2b(v0), h1 = f2b(v1);
    const unsigned short l0 = f2b(v0 - b2f(h0)), l1 = f2b(v1 - b2f(h1));
    *(unsigned int*)(bH + t) = (unsigned)h0 | ((unsigned)h1 << 16);
    *(unsigned int*)(bL + t) = (unsigned)l0 | ((unsigned)l1 << 16);
}

// ============ stage 2: fused GEMM (split-bf16 MFMA) + col-softmax + matvec ============
// grid 256 (fm), block 1024 = 16 waves; wave w owns j = w*4..w*4+3, unrolled 2x for ILP.
__launch_bounds__(1024, 4)
__global__ void fused_mfma(const float* __restrict__ x,
                           const unsigned short* __restrict__ bH,
                           const unsigned short* __restrict__ bL,
                           float* __restrict__ out,
                           int* __restrict__ flag) {
    __shared__ float xT[FF][17];         // xT[j][bl_local]  4.4 KB
    __shared__ float part[16][FF][17];   // per-wave out partials [i][bl_local]  69.6 KB
    __shared__ float wmn[16];

    const int tid = threadIdx.x;
    const int w = tid >> 6, lane = tid & 63;
    const int fm = blockIdx.x;          // 0..255
    const int bl0 = fm * 16;
    const int hi4 = lane >> 4;          // 0..3
    const int c15 = lane & 15;

    {   // stage xT (single pass, 1024 threads)
        const int bl_local = tid >> 6, j = tid & 63;
        xT[j][bl_local] = x[(size_t)(bl0 + bl_local) * FF + j];
    }

    // build own A fragments in registers (verified r8-r10)
    short8 aH[2], aL[2];
    #pragma unroll
    for (int ks = 0; ks < 2; ++ks) {
        const float* xp = x + (size_t)(bl0 + c15) * FF + ks * 32 + hi4 * 8;
        const float4 v0 = *(const float4*)xp;
        const float4 v1 = *(const float4*)(xp + 4);
        float vv[8] = {v0.x, v0.y, v0.z, v0.w, v1.x, v1.y, v1.z, v1.w};
        unsigned short hh[8], ll[8];
        #pragma unroll
        for (int e = 0; e < 8; ++e) {
            hh[e] = f2b(vv[e]);
            ll[e] = f2b(vv[e] - b2f(hh[e]));
        }
        aH[ks] = *(const short8*)hh;
        aL[ks] = *(const short8*)ll;
    }
    __syncthreads();

    f32x4 racc[4];
    #pragma unroll
    for (int q = 0; q < 4; ++q) racc[q] = (f32x4){0.f, 0.f, 0.f, 0.f};
    f32x4 mn4 = (f32x4){INFINITY, INFINITY, INFINITY, INFINITY};

    const bool wrT = ((fm & 7) == 7) && (hi4 == 3);
    float* out1 = out + (size_t)BB * LL * FF + (size_t)(fm >> 3) * NIJ;

    #pragma unroll 2
    for (int jj = 0; jj < 4; ++jj) {
        const int j = w * 4 + jj;
        f32x4 acc[4];
        #pragma unroll
        for (int q = 0; q < 4; ++q) acc[q] = (f32x4){0.f, 0.f, 0.f, 0.f};
        #pragma unroll
        for (int ks = 0; ks < 2; ++ks) {
            #pragma unroll
            for (int q = 0; q < 4; ++q) {
                const size_t bb = (((size_t)ks * 256 + j * 4 + q) * 64 + lane) * 8;
                const short8 bHf = *(const short8*)(bH + bb);
                const short8 bLf = *(const short8*)(bL + bb);
                acc[q] = __builtin_amdgcn_mfma_f32_16x16x32_bf16(aH[ks], bHf, acc[q], 0, 0, 0);
                acc[q] = __builtin_amdgcn_mfma_f32_16x16x32_bf16(aH[ks], bLf, acc[q], 0, 0, 0);
                acc[q] = __builtin_amdgcn_mfma_f32_16x16x32_bf16(aL[ks], bHf, acc[q], 0, 0, 0);
            }
        }
        // z = 7*D0 ; softmax over i = {16 lanes} x {4 frags}
        f32x4 z[4], mxv;
        #pragma unroll
        for (int q = 0; q < 4; ++q) {
            z[q] = acc[q] * 7.0f;
            #pragma unroll
            for (int c = 0; c < 4; ++c) mn4[c] = fminf(mn4[c], z[q][c]);
        }
        #pragma unroll
        for (int c = 0; c < 4; ++c)
            mxv[c] = fmaxf(fmaxf(z[0][c], z[1][c]), fmaxf(z[2][c], z[3][c]));
        #pragma unroll
        for (int o = 1; o < 16; o <<= 1)
            #pragma unroll
            for (int c = 0; c < 4; ++c) mxv[c] = fmaxf(mxv[c], __shfl_xor(mxv[c], o));
        f32x4 e[4], s = (f32x4){0.f, 0.f, 0.f, 0.f};
        #pragma unroll
        for (int q = 0; q < 4; ++q) {
            #pragma unroll
            for (int c = 0; c < 4; ++c) e[q][c] = __expf(z[q][c] - mxv[c]);
            s += e[q];
        }
        #pragma unroll
        for (int o = 1; o < 16; o <<= 1)
            #pragma unroll
            for (int c = 0; c < 4; ++c) s[c] += __shfl_xor(s[c], o);
        f32x4 inv;
        #pragma unroll
        for (int c = 0; c < 4; ++c) inv[c] = 1.0f / s[c];
        f32x4 xbv;
        #pragma unroll
        for (int c = 0; c < 4; ++c) xbv[c] = xT[j][hi4 * 4 + c];
        #pragma unroll
        for (int q = 0; q < 4; ++q) {
            const f32x4 wq = e[q] * inv;
            racc[q] += wq * xbv;
            if (wrT) out1[(q * 16 + c15) * 64 + j] = wq[3];   // bl_local 15 -> l=127
        }
    }

    #pragma unroll
    for (int q = 0; q < 4; ++q)
        #pragma unroll
        for (int r = 0; r < 4; ++r)
            part[w][q * 16 + c15][hi4 * 4 + r] = racc[q][r];

    float mn = fminf(fminf(mn4[0], mn4[1]), fminf(mn4[2], mn4[3]));
    #pragma unroll
    for (int o = 1; o < 64; o <<= 1) mn = fminf(mn, __shfl_xor(mn, o));
    if (lane == 0) wmn[w] = mn;
    __syncthreads();

    {   // deterministic cross-wave j-reduction (single pass, 1024 threads)
        const int bl_local = tid >> 6, i = tid & 63;
        float a = 0.f;
        #pragma unroll
        for (int ww = 0; ww < 16; ++ww) a += part[ww][i][bl_local];
        out[(size_t)(bl0 + bl_local) * FF + i] = a;
    }
    if (tid == 0) {
        float m2 = wmn[0];
        #pragma unroll
        for (int ww = 1; ww < 16; ++ww) m2 = fminf(m2, wmn[ww]);
        if (!(m2 >= 10.5f)) atomicOr(flag, 1);   // also catches NaN
    }
}

// ============ fallback slab build (small-ws path only) ============
__global__ void build_slab0(const float* __restrict__ inter, float* __restrict__ slab0T) {
    int t = blockIdx.x * blockDim.x + threadIdx.x;
    if (t < FF * FF * FF) {
        int m = t >> 12;
        int ij = t & 4095;
        slab0T[t] = inter[((size_t)ij * FF + m) * FP1];
    }
}

// ==================== exact sequential fallback / repair (verified round-1) ====================
__launch_bounds__(1024, 1)
__global__ void coil_main(const float* __restrict__ x,
                          const float* __restrict__ inter,
                          const float* __restrict__ slab0T,
                          float* __restrict__ out,
                          int useSlab,
                          const int* __restrict__ flag) {
    if (flag && *flag == 0) return;   // certificate held: parallel path already correct

    __shared__ float Tlds[FF][FP1];
    __shared__ float selr[FF][FP1];
    __shared__ float s_l[FF], hiW[FF], loW[FF];
    __shared__ float zsc[FP1], swW[FP1], scoresAcc[FP1];
    __shared__ float chunkA[8][FP1 + 3];
    __shared__ int IL[FF], JL[FF];
    __shared__ int nIJ[2];
    __shared__ int Klist[FP1];
    __shared__ float Kw[FP1];
    __shared__ int nK;
    __shared__ float redmx;

    const int b = blockIdx.x;
    const int tid = threadIdx.x;
    const int wave = tid >> 6;
    const int lane = tid & 63;

    for (int idx = tid; idx < FF * FP1; idx += 1024)
        ((float*)Tlds)[idx] = 1.0f / FF;

    const float* xb = x + (size_t)b * LL * FF;
    float* out0 = out + (size_t)b * LL * FF;
    float* out1 = out + (size_t)BB * LL * FF + (size_t)b * FF * FF;

    for (int l = 0; l < LL; ++l) {
        __syncthreads();
        if (tid < FF) s_l[tid] = xb[l * FF + tid];
        __syncthreads();
        if (wave == 0) {
            float z = s_l[lane] / 0.001f;
            float mx = z;
            for (int o = 32; o > 0; o >>= 1) mx = fmaxf(mx, __shfl_xor(mx, o));
            float e = expf(z - mx);
            float sm = e;
            for (int o = 32; o > 0; o >>= 1) sm += __shfl_xor(sm, o);
            float w = e / sm;
            hiW[lane] = w;
            unsigned long long msk = __ballot(w > 1e-16f);
            int pos = (int)__popcll(msk & ((1ull << lane) - 1ull));
            if (w > 1e-16f) JL[pos] = lane;
            if (lane == 0) nIJ[1] = (int)__popcll(msk);
        } else if (wave == 1) {
            float z = 1.0f - s_l[lane] / 0.001f;
            float mx = z;
            for (int o = 32; o > 0; o >>= 1) mx = fmaxf(mx, __shfl_xor(mx, o));
            float e = expf(z - mx);
            float sm = e;
            for (int o = 32; o > 0; o >>= 1) sm += __shfl_xor(sm, o);
            float w = e / sm;
            loW[lane] = w;
            unsigned long long msk = __ballot(w > 1e-16f);
            int pos = (int)__popcll(msk & ((1ull << lane) - 1ull));
            if (w > 1e-16f) IL[pos] = lane;
            if (lane == 0) nIJ[0] = (int)__popcll(msk);
        }
        if (tid < FP1) scoresAcc[tid] = 0.0f;
        __syncthreads();

        const int nI = nIJ[0], nJ = nIJ[1];
        const int npairs = nI * nJ;
        for (int pbase = 0; pbase < npairs; pbase += 8) {
            int prem = npairs - pbase; if (prem > 8) prem = 8;
            int p_local = wave >> 1, half = wave & 1;
            if (p_local < prem) {
                int p = pbase + p_local;
                int i = IL[p / nJ];
                int jx = JL[p % nJ];
                float vv = loW[i] * hiW[jx];
                int k = half * 32 + lane;
                bool act = half ? (lane < 33) : (lane < 32);
                if (act) {
                    const float* base = inter + (size_t)(i * FF + jx) * (FF * FP1) + k;
                    const float* nsv = (k == 0) ? s_l : &Tlds[k - 1][0];
                    float acc = 0.0f;
                    #pragma unroll 16
                    for (int m = 0; m < FF; ++m) acc += base[m * FP1] * nsv[m];
                    chunkA[p_local][k] = vv * acc;
                }
            }
            __syncthreads();
            if (tid < FP1) {
                float a = scoresAcc[tid];
                for (int pl = 0; pl < prem; ++pl) a += chunkA[pl][tid];
                scoresAcc[tid] = a;
            }
            __syncthreads();
        }
        if (tid < FP1) zsc[tid] = scoresAcc[tid] / 0.001f;
        __syncthreads();
        if (tid == 0) {
            float mx = zsc[0];
            for (int k = 1; k < FP1; ++k) mx = fmaxf(mx, zsc[k]);
            redmx = mx;
        }
        __syncthreads();
        if (tid < FP1) zsc[tid] = expf(zsc[tid] - redmx);
        __syncthreads();
        if (tid == 0) {
            float sm = 0.0f;
            for (int k = 0; k < FP1; ++k) sm += zsc[k];
            int cnt = 0;
            for (int k = 0; k < FP1; ++k) {
                float w = zsc[k] / sm;
                swW[k] = w;
                if (w > 1e-14f) { Klist[cnt] = k; Kw[cnt] = w; ++cnt; }
            }
            nK = cnt;
        }
        __syncthreads();

        float ax = 0.f, ay = 0.f, az = 0.f, aw = 0.f;
        const int ij0 = tid * 4;
        for (int kk = 0; kk < nK; ++kk) {
            int k = Klist[kk];
            float wk = Kw[kk];
            float dx = 0.f, dy = 0.f, dz = 0.f, dw = 0.f;
            if (k == 0 && useSlab) {
                const float4* sp = (const float4*)slab0T;
                #pragma unroll 8
                for (int m = 0; m < FF; ++m) {
                    float4 f = sp[m * (FF * FF / 4) + tid];
                    float ns = s_l[m];
                    dx += f.x * ns; dy += f.y * ns; dz += f.z * ns; dw += f.w * ns;
                }
            } else {
                const float* nsv = (k == 0) ? s_l : &Tlds[k - 1][0];
                const float* bp = inter + (size_t)ij0 * (FF * FP1) + k;
                #pragma unroll 8
                for (int m = 0; m < FF; ++m) {
                    float ns = nsv[m];
                    dx += bp[m * FP1] * ns;
                    dy += bp[m * FP1 + FF * FP1] * ns;
                    dz += bp[m * FP1 + 2 * FF * FP1] * ns;
                    dw += bp[m * FP1 + 3 * FF * FP1] * ns;
                }
            }
            ax += wk * dx; ay += wk * dy; az += wk * dz; aw += wk * dw;
        }
        {
            int ii = tid >> 4;
            int jj = (tid & 15) * 4;
            selr[jj + 0][ii] = ax; selr[jj + 1][ii] = ay;
            selr[jj + 2][ii] = az; selr[jj + 3][ii] = aw;
        }
        __syncthreads();
        if (tid < FF) {
            int jcol = tid;
            float mx = -INFINITY;
            for (int i2 = 0; i2 < FF; ++i2) mx = fmaxf(mx, selr[jcol][i2] * 7.0f);
            float sm = 0.0f;
            for (int i2 = 0; i2 < FF; ++i2) {
                float e = expf(selr[jcol][i2] * 7.0f - mx);
                selr[jcol][i2] = e; sm += e;
            }
            for (int i2 = 0; i2 < FF; ++i2) Tlds[jcol][i2] = selr[jcol][i2] / sm;
        }
        __syncthreads();
        if (tid < FF) {
            float acc2 = 0.0f;
            for (int j2 = 0; j2 < FF; ++j2) acc2 += Tlds[j2][tid] * s_l[j2];
            out0[l * FF + tid] = acc2;
        }
    }
    __syncthreads();
    for (int idx = tid; idx < FF * FF; idx += 1024) {
        int i2 = idx >> 6, j2 = idx & 63;
        out1[idx] = Tlds[j2][i2];
    }
}

extern "C" void kernel_launch(void* const* d_in, const int* in_sizes, int n_in,
                              void* d_out, int out_size, void* d_ws, size_t ws_size,
                              hipStream_t stream) {
    const float* x = (const float*)d_in[0];
    const float* inter = (const float*)d_in[1];
    float* outp = (float*)d_out;
    char* ws = (char*)d_ws;

    if (ws_size >= WS_NEED) {
        unsigned short* bH = (unsigned short*)(ws + OFF_BH);
        unsigned short* bL = (unsigned short*)(ws + OFF_BL);
        int* flag = (int*)(ws + OFF_FLAG);

        build_slabB<<<dim3(512), dim3(256), 0, stream>>>(inter, bH, bL, flag);
        fused_mfma<<<dim3(256), dim3(1024), 0, stream>>>(x, bH, bL, outp, flag);
        // repair: no-op when certificate holds; exact recompute otherwise
        coil_main<<<dim3(BB), dim3(1024), 0, stream>>>(x, inter, (const float*)0, outp, 0, flag);
    } else {
        float* slab0T = (float*)ws;
        int useSlab = (ws_size >= (size_t)FF * FF * FF * sizeof(float)) ? 1 : 0;
        if (useSlab)
            build_slab0<<<dim3(1024), dim3(256), 0, stream>>>(inter, slab0T);
        coil_main<<<dim3(BB), dim3(1024), 0, stream>>>(x, inter, slab0T, outp, useSlab, (const int*)0);
    }
}

// Round 13
// 30.523 us; speedup vs baseline: 1.3692x; 1.1336x over previous
//
#include <hip/hip_runtime.h>
#include <math.h>

#define FF 64
#define FP1 65
#define BB 32
#define LL 128
#define NBL 4096        // BB*LL
#define NIJ 4096        // FF*FF

typedef __attribute__((ext_vector_type(8))) short short8;
typedef __attribute__((ext_vector_type(4))) float f32x4;

__device__ __forceinline__ unsigned short f2b(float f) {   // f32 -> bf16 RNE
    union { float f; unsigned u; } v; v.f = f;
    unsigned r = v.u + 0x7fffu + ((v.u >> 16) & 1u);
    return (unsigned short)(r >> 16);
}
__device__ __forceinline__ float b2f(unsigned short h) {
    union { unsigned u; float f; } v; v.u = ((unsigned)h) << 16; return v.f;
}

// ---- ws layout (bytes) ----
#define OFF_BH   0ull            // slabB hi (j-major B-frags) 512 KB
#define OFF_BL   524288ull       // slabB lo 512 KB
#define OFF_FLAG 1048576ull      // 4 B
#define WS_NEED  1048640ull

// ============ stage 1: slab k=0 slice -> bf16 hi/lo B-fragments (n = j*64+i); zero flag ============
__global__ void build_slabB(const float* __restrict__ inter,
                            unsigned short* __restrict__ bH,
                            unsigned short* __restrict__ bL,
                            int* __restrict__ flag) {
    const size_t t = (size_t)blockIdx.x * 256 + threadIdx.x;   // 262144 total
    if (t == 0) *flag = 0;
    const int e = (int)(t & 7);
    const int lane = (int)((t >> 3) & 63);
    const int fn = (int)((t >> 9) & 255);
    const int ks = (int)(t >> 17);
    const int n = fn * 16 + (lane & 15);
    const int i = n & 63;
    const int j = n >> 6;
    const int m = ks * 32 + ((lane >> 4) & 3) * 8 + e;
    const float v = inter[((size_t)(i * FF + j) * FF + m) * FP1];
    const unsigned short h = f2b(v);
    bH[t] = h;
    bL[t] = f2b(v - b2f(h));
}

// ============ stage 2: fused GEMM (split-bf16 MFMA) + col-softmax + matvec ============
// grid 256 (fm), block 1024 = 16 waves; wave w owns j = w*4..w*4+3; block owns 16 bl rows.
// 16 waves/CU (vs 8 in r9) + halved per-wave serial softmax chain.  [r10 verified: 30.6 us]
__launch_bounds__(1024, 4)
__global__ void fused_mfma(const float* __restrict__ x,
                           const unsigned short* __restrict__ bH,
                           const unsigned short* __restrict__ bL,
                           float* __restrict__ out,
                           int* __restrict__ flag) {
    __shared__ float xT[FF][17];         // xT[j][bl_local]  4.4 KB
    __shared__ float part[16][FF][17];   // per-wave out partials [i][bl_local]  69.6 KB
    __shared__ float wmn[16];

    const int tid = threadIdx.x;
    const int w = tid >> 6, lane = tid & 63;
    const int fm = blockIdx.x;          // 0..255
    const int bl0 = fm * 16;
    const int hi4 = lane >> 4;          // 0..3
    const int c15 = lane & 15;

    {   // stage xT (single pass, 1024 threads)
        const int bl_local = tid >> 6, j = tid & 63;
        xT[j][bl_local] = x[(size_t)(bl0 + bl_local) * FF + j];
    }

    // build own A fragments in registers (verified r8/r9)
    short8 aH[2], aL[2];
    #pragma unroll
    for (int ks = 0; ks < 2; ++ks) {
        const float* xp = x + (size_t)(bl0 + c15) * FF + ks * 32 + hi4 * 8;
        const float4 v0 = *(const float4*)xp;
        const float4 v1 = *(const float4*)(xp + 4);
        float vv[8] = {v0.x, v0.y, v0.z, v0.w, v1.x, v1.y, v1.z, v1.w};
        unsigned short hh[8], ll[8];
        #pragma unroll
        for (int e = 0; e < 8; ++e) {
            hh[e] = f2b(vv[e]);
            ll[e] = f2b(vv[e] - b2f(hh[e]));
        }
        aH[ks] = *(const short8*)hh;
        aL[ks] = *(const short8*)ll;
    }
    __syncthreads();

    f32x4 racc[4];
    #pragma unroll
    for (int q = 0; q < 4; ++q) racc[q] = (f32x4){0.f, 0.f, 0.f, 0.f};
    f32x4 mn4 = (f32x4){INFINITY, INFINITY, INFINITY, INFINITY};

    const bool wrT = ((fm & 7) == 7) && (hi4 == 3);
    float* out1 = out + (size_t)BB * LL * FF + (size_t)(fm >> 3) * NIJ;

    #pragma unroll 1
    for (int jj = 0; jj < 4; ++jj) {
        const int j = w * 4 + jj;
        f32x4 acc[4];
        #pragma unroll
        for (int q = 0; q < 4; ++q) acc[q] = (f32x4){0.f, 0.f, 0.f, 0.f};
        #pragma unroll
        for (int ks = 0; ks < 2; ++ks) {
            #pragma unroll
            for (int q = 0; q < 4; ++q) {
                const size_t bb = (((size_t)ks * 256 + j * 4 + q) * 64 + lane) * 8;
                const short8 bHf = *(const short8*)(bH + bb);
                const short8 bLf = *(const short8*)(bL + bb);
                acc[q] = __builtin_amdgcn_mfma_f32_16x16x32_bf16(aH[ks], bHf, acc[q], 0, 0, 0);
                acc[q] = __builtin_amdgcn_mfma_f32_16x16x32_bf16(aH[ks], bLf, acc[q], 0, 0, 0);
                acc[q] = __builtin_amdgcn_mfma_f32_16x16x32_bf16(aL[ks], bHf, acc[q], 0, 0, 0);
            }
        }
        // z = 7*D0 ; softmax over i = {16 lanes} x {4 frags}
        f32x4 z[4], mxv;
        #pragma unroll
        for (int q = 0; q < 4; ++q) {
            z[q] = acc[q] * 7.0f;
            #pragma unroll
            for (int c = 0; c < 4; ++c) mn4[c] = fminf(mn4[c], z[q][c]);
        }
        #pragma unroll
        for (int c = 0; c < 4; ++c)
            mxv[c] = fmaxf(fmaxf(z[0][c], z[1][c]), fmaxf(z[2][c], z[3][c]));
        #pragma unroll
        for (int o = 1; o < 16; o <<= 1)
            #pragma unroll
            for (int c = 0; c < 4; ++c) mxv[c] = fmaxf(mxv[c], __shfl_xor(mxv[c], o));
        f32x4 e[4], s = (f32x4){0.f, 0.f, 0.f, 0.f};
        #pragma unroll
        for (int q = 0; q < 4; ++q) {
            #pragma unroll
            for (int c = 0; c < 4; ++c) e[q][c] = __expf(z[q][c] - mxv[c]);
            s += e[q];
        }
        #pragma unroll
        for (int o = 1; o < 16; o <<= 1)
            #pragma unroll
            for (int c = 0; c < 4; ++c) s[c] += __shfl_xor(s[c], o);
        f32x4 inv;
        #pragma unroll
        for (int c = 0; c < 4; ++c) inv[c] = 1.0f / s[c];
        f32x4 xbv;
        #pragma unroll
        for (int c = 0; c < 4; ++c) xbv[c] = xT[j][hi4 * 4 + c];
        #pragma unroll
        for (int q = 0; q < 4; ++q) {
            const f32x4 wq = e[q] * inv;
            racc[q] += wq * xbv;
            if (wrT) out1[(q * 16 + c15) * 64 + j] = wq[3];   // bl_local 15 -> l=127
        }
    }

    #pragma unroll
    for (int q = 0; q < 4; ++q)
        #pragma unroll
        for (int r = 0; r < 4; ++r)
            part[w][q * 16 + c15][hi4 * 4 + r] = racc[q][r];

    float mn = fminf(fminf(mn4[0], mn4[1]), fminf(mn4[2], mn4[3]));
    #pragma unroll
    for (int o = 1; o < 64; o <<= 1) mn = fminf(mn, __shfl_xor(mn, o));
    if (lane == 0) wmn[w] = mn;
    __syncthreads();

    {   // deterministic cross-wave j-reduction (single pass, 1024 threads)
        const int bl_local = tid >> 6, i = tid & 63;
        float a = 0.f;
        #pragma unroll
        for (int ww = 0; ww < 16; ++ww) a += part[ww][i][bl_local];
        out[(size_t)(bl0 + bl_local) * FF + i] = a;
    }
    if (tid == 0) {
        float m2 = wmn[0];
        #pragma unroll
        for (int ww = 1; ww < 16; ++ww) m2 = fminf(m2, wmn[ww]);
        if (!(m2 >= 10.5f)) atomicOr(flag, 1);   // also catches NaN
    }
}

// ============ fallback slab build (small-ws path only) ============
__global__ void build_slab0(const float* __restrict__ inter, float* __restrict__ slab0T) {
    int t = blockIdx.x * blockDim.x + threadIdx.x;
    if (t < FF * FF * FF) {
        int m = t >> 12;
        int ij = t & 4095;
        slab0T[t] = inter[((size_t)ij * FF + m) * FP1];
    }
}

// ==================== exact sequential fallback / repair (verified round-1) ====================
__launch_bounds__(1024, 1)
__global__ void coil_main(const float* __restrict__ x,
                          const float* __restrict__ inter,
                          const float* __restrict__ slab0T,
                          float* __restrict__ out,
                          int useSlab,
                          const int* __restrict__ flag) {
    if (flag && *flag == 0) return;   // certificate held: parallel path already correct

    __shared__ float Tlds[FF][FP1];
    __shared__ float selr[FF][FP1];
    __shared__ float s_l[FF], hiW[FF], loW[FF];
    __shared__ float zsc[FP1], swW[FP1], scoresAcc[FP1];
    __shared__ float chunkA[8][FP1 + 3];
    __shared__ int IL[FF], JL[FF];
    __shared__ int nIJ[2];
    __shared__ int Klist[FP1];
    __shared__ float Kw[FP1];
    __shared__ int nK;
    __shared__ float redmx;

    const int b = blockIdx.x;
    const int tid = threadIdx.x;
    const int wave = tid >> 6;
    const int lane = tid & 63;

    for (int idx = tid; idx < FF * FP1; idx += 1024)
        ((float*)Tlds)[idx] = 1.0f / FF;

    const float* xb = x + (size_t)b * LL * FF;
    float* out0 = out + (size_t)b * LL * FF;
    float* out1 = out + (size_t)BB * LL * FF + (size_t)b * FF * FF;

    for (int l = 0; l < LL; ++l) {
        __syncthreads();
        if (tid < FF) s_l[tid] = xb[l * FF + tid];
        __syncthreads();
        if (wave == 0) {
            float z = s_l[lane] / 0.001f;
            float mx = z;
            for (int o = 32; o > 0; o >>= 1) mx = fmaxf(mx, __shfl_xor(mx, o));
            float e = expf(z - mx);
            float sm = e;
            for (int o = 32; o > 0; o >>= 1) sm += __shfl_xor(sm, o);
            float w = e / sm;
            hiW[lane] = w;
            unsigned long long msk = __ballot(w > 1e-16f);
            int pos = (int)__popcll(msk & ((1ull << lane) - 1ull));
            if (w > 1e-16f) JL[pos] = lane;
            if (lane == 0) nIJ[1] = (int)__popcll(msk);
        } else if (wave == 1) {
            float z = 1.0f - s_l[lane] / 0.001f;
            float mx = z;
            for (int o = 32; o > 0; o >>= 1) mx = fmaxf(mx, __shfl_xor(mx, o));
            float e = expf(z - mx);
            float sm = e;
            for (int o = 32; o > 0; o >>= 1) sm += __shfl_xor(sm, o);
            float w = e / sm;
            loW[lane] = w;
            unsigned long long msk = __ballot(w > 1e-16f);
            int pos = (int)__popcll(msk & ((1ull << lane) - 1ull));
            if (w > 1e-16f) IL[pos] = lane;
            if (lane == 0) nIJ[0] = (int)__popcll(msk);
        }
        if (tid < FP1) scoresAcc[tid] = 0.0f;
        __syncthreads();

        const int nI = nIJ[0], nJ = nIJ[1];
        const int npairs = nI * nJ;
        for (int pbase = 0; pbase < npairs; pbase += 8) {
            int prem = npairs - pbase; if (prem > 8) prem = 8;
            int p_local = wave >> 1, half = wave & 1;
            if (p_local < prem) {
                int p = pbase + p_local;
                int i = IL[p / nJ];
                int jx = JL[p % nJ];
                float vv = loW[i] * hiW[jx];
                int k = half * 32 + lane;
                bool act = half ? (lane < 33) : (lane < 32);
                if (act) {
                    const float* base = inter + (size_t)(i * FF + jx) * (FF * FP1) + k;
                    const float* nsv = (k == 0) ? s_l : &Tlds[k - 1][0];
                    float acc = 0.0f;
                    #pragma unroll 16
                    for (int m = 0; m < FF; ++m) acc += base[m * FP1] * nsv[m];
                    chunkA[p_local][k] = vv * acc;
                }
            }
            __syncthreads();
            if (tid < FP1) {
                float a = scoresAcc[tid];
                for (int pl = 0; pl < prem; ++pl) a += chunkA[pl][tid];
                scoresAcc[tid] = a;
            }
            __syncthreads();
        }
        if (tid < FP1) zsc[tid] = scoresAcc[tid] / 0.001f;
        __syncthreads();
        if (tid == 0) {
            float mx = zsc[0];
            for (int k = 1; k < FP1; ++k) mx = fmaxf(mx, zsc[k]);
            redmx = mx;
        }
        __syncthreads();
        if (tid < FP1) zsc[tid] = expf(zsc[tid] - redmx);
        __syncthreads();
        if (tid == 0) {
            float sm = 0.0f;
            for (int k = 0; k < FP1; ++k) sm += zsc[k];
            int cnt = 0;
            for (int k = 0; k < FP1; ++k) {
                float w = zsc[k] / sm;
                swW[k] = w;
                if (w > 1e-14f) { Klist[cnt] = k; Kw[cnt] = w; ++cnt; }
            }
            nK = cnt;
        }
        __syncthreads();

        float ax = 0.f, ay = 0.f, az = 0.f, aw = 0.f;
        const int ij0 = tid * 4;
        for (int kk = 0; kk < nK; ++kk) {
            int k = Klist[kk];
            float wk = Kw[kk];
            float dx = 0.f, dy = 0.f, dz = 0.f, dw = 0.f;
            if (k == 0 && useSlab) {
                const float4* sp = (const float4*)slab0T;
                #pragma unroll 8
                for (int m = 0; m < FF; ++m) {
                    float4 f = sp[m * (FF * FF / 4) + tid];
                    float ns = s_l[m];
                    dx += f.x * ns; dy += f.y * ns; dz += f.z * ns; dw += f.w * ns;
                }
            } else {
                const float* nsv = (k == 0) ? s_l : &Tlds[k - 1][0];
                const float* bp = inter + (size_t)ij0 * (FF * FP1) + k;
                #pragma unroll 8
                for (int m = 0; m < FF; ++m) {
                    float ns = nsv[m];
                    dx += bp[m * FP1] * ns;
                    dy += bp[m * FP1 + FF * FP1] * ns;
                    dz += bp[m * FP1 + 2 * FF * FP1] * ns;
                    dw += bp[m * FP1 + 3 * FF * FP1] * ns;
                }
            }
            ax += wk * dx; ay += wk * dy; az += wk * dz; aw += wk * dw;
        }
        {
            int ii = tid >> 4;
            int jj = (tid & 15) * 4;
            selr[jj + 0][ii] = ax; selr[jj + 1][ii] = ay;
            selr[jj + 2][ii] = az; selr[jj + 3][ii] = aw;
        }
        __syncthreads();
        if (tid < FF) {
            int jcol = tid;
            float mx = -INFINITY;
            for (int i2 = 0; i2 < FF; ++i2) mx = fmaxf(mx, selr[jcol][i2] * 7.0f);
            float sm = 0.0f;
            for (int i2 = 0; i2 < FF; ++i2) {
                float e = expf(selr[jcol][i2] * 7.0f - mx);
                selr[jcol][i2] = e; sm += e;
            }
            for (int i2 = 0; i2 < FF; ++i2) Tlds[jcol][i2] = selr[jcol][i2] / sm;
        }
        __syncthreads();
        if (tid < FF) {
            float acc2 = 0.0f;
            for (int j2 = 0; j2 < FF; ++j2) acc2 += Tlds[j2][tid] * s_l[j2];
            out0[l * FF + tid] = acc2;
        }
    }
    __syncthreads();
    for (int idx = tid; idx < FF * FF; idx += 1024) {
        int i2 = idx >> 6, j2 = idx & 63;
        out1[idx] = Tlds[j2][i2];
    }
}

extern "C" void kernel_launch(void* const* d_in, const int* in_sizes, int n_in,
                              void* d_out, int out_size, void* d_ws, size_t ws_size,
                              hipStream_t stream) {
    const float* x = (const float*)d_in[0];
    const float* inter = (const float*)d_in[1];
    float* outp = (float*)d_out;
    char* ws = (char*)d_ws;

    if (ws_size >= WS_NEED) {
        unsigned short* bH = (unsigned short*)(ws + OFF_BH);
        unsigned short* bL = (unsigned short*)(ws + OFF_BL);
        int* flag = (int*)(ws + OFF_FLAG);

        build_slabB<<<dim3(1024), dim3(256), 0, stream>>>(inter, bH, bL, flag);
        fused_mfma<<<dim3(256), dim3(1024), 0, stream>>>(x, bH, bL, outp, flag);
        // repair: no-op when certificate holds; exact recompute otherwise
        coil_main<<<dim3(BB), dim3(1024), 0, stream>>>(x, inter, (const float*)0, outp, 0, flag);
    } else {
        float* slab0T = (float*)ws;
        int useSlab = (ws_size >= (size_t)FF * FF * FF * sizeof(float)) ? 1 : 0;
        if (useSlab)
            build_slab0<<<dim3(1024), dim3(256), 0, stream>>>(inter, slab0T);
        coil_main<<<dim3(BB), dim3(1024), 0, stream>>>(x, inter, slab0T, outp, useSlab, (const int*)0);
    }
}